// Round 4
// baseline (246.208 us; speedup 1.0000x reference)
//
#include <hip/hip_runtime.h>

#define NN 50000
#define NE 250000
#define NT 7813        // ceil(NE/32)
#define NBH 768        // edge blocks per K-half

typedef __attribute__((ext_vector_type(8)))  short    s16x8;
typedef __attribute__((ext_vector_type(16))) float    f32x16;
typedef __attribute__((ext_vector_type(4)))  unsigned u32x4;

__device__ __forceinline__ unsigned bf16r(float f) {
    unsigned u = __float_as_uint(f);
    return (u + 0x7fffu + ((u >> 16) & 1u)) >> 16;   // RNE
}
__device__ __forceinline__ short bfs(float f) {
    __bf16 b = (__bf16)f;
    return __builtin_bit_cast(short, b);
}

// ---------------------------------------------------------------------------
// prep: pack w2ext (w2 rows + b2 rows) into TWO half-images of bf16 B-fragments
// and zero agg (d_out) + cnt. Half kh, local step s in [0,33):
//   global step S = (s<32) ? 32*kh+s : 64+kh; covers w2ext rows [16S,16S+16)
//   image dword index: kh*8448 + s*256 + lane*4 + q
// ---------------------------------------------------------------------------
__global__ __launch_bounds__(256) void prep_kernel(
    const float* __restrict__ w2, const float* __restrict__ b2,
    unsigned* __restrict__ w2pk, float* __restrict__ agg,
    float* __restrict__ cnt)
{
    int g = blockIdx.x * 256 + threadIdx.x;
    if (g < 16896) {
        int kh = g / 8448, rem = g % 8448;
        int s = rem >> 8, l = (rem >> 2) & 63, q = rem & 3;
        int S = (s < 32) ? 32 * kh + s : 64 + kh;
        int col = l & 31;
        int kk = S * 16 + (l >> 5) * 8 + 2 * q;
        float f0 = (kk < 1024) ? w2[(kk >> 5) * 1024 + (kk & 31) * 32 + col]
                               : b2[(kk - 1024) * 32 + col];
        int k1 = kk + 1;
        float f1 = (k1 < 1024) ? w2[(k1 >> 5) * 1024 + (k1 & 31) * 32 + col]
                               : b2[(k1 - 1024) * 32 + col];
        w2pk[g] = (bf16r(f1) << 16) | bf16r(f0);
    } else {
        int c = g - 16896;
        if (c < 400000)      ((float4*)agg)[c]          = float4{0.f,0.f,0.f,0.f};
        else if (c < 412500) ((float4*)cnt)[c - 400000] = float4{0.f,0.f,0.f,0.f};
    }
}

// ---------------------------------------------------------------------------
// edge kernel, K-split: block handles k in [16*kh, 16*kh+16).
//  hT = mfma(w1f, eaf): D[row=k][col=e]  (A/B fragments are layout-identical;
//  validated by round 2's pass).
//  Half-exchange via __shfl_xor(.,32) + cndmask (semantics-certain, unlike
//  v_permlane32_swap whose direction failed round 3).
//  33 MFMA accumulate the partial msg tile; atomicAdd into agg.
// ---------------------------------------------------------------------------
__global__ __launch_bounds__(512, 6) void edge_kernel(
    const float* __restrict__ x, const int* __restrict__ ei,
    const float* __restrict__ ea, const float* __restrict__ w1,
    const float* __restrict__ b1, const unsigned* __restrict__ w2pk,
    float* __restrict__ agg, float* __restrict__ cnt)
{
    __shared__ unsigned sw2[33 * 256];            // 33792 B
    const int kh    = blockIdx.x & 1;
    const int bslot = blockIdx.x >> 1;            // 0..NBH-1
    {
        const u32x4* srcp = (const u32x4*)(w2pk + kh * 8448);
        u32x4* dstp = (u32x4*)sw2;
        for (int c = threadIdx.x; c < 2112; c += 512) dstp[c] = srcp[c];
    }
    __syncthreads();

    const int lane = threadIdx.x & 63;
    const int wave = threadIdx.x >> 6;
    const int er0  = lane & 31;     // edge row (A/D), hid col (B/D), h col
    const int half = lane >> 5;

    // w1 B-fragment (16x32): lane l -> w1[(l>>5)*8+j][l&31]
    s16x8 w1f;
    #pragma unroll
    for (int j = 0; j < 8; j++) w1f[j] = bfs(w1[(half * 8 + j) * 32 + er0]);
    // b1 for own hc elements
    float b1r[8];
    #pragma unroll
    for (int i = 0; i < 8; i++)
        b1r[i] = b1[16 * kh + (i & 3) + 8 * (i >> 2) + 4 * half];

    const int ws0 = ((bslot * 8 + wave) + kh * (NBH * 4)) % (NBH * 8);

    for (int tile = ws0; tile < NT; tile += NBH * 8) {
        const int B0  = tile * 32;
        const int eg  = B0 + er0;
        const int egc = eg < NE ? eg : NE - 1;
        const int src = ei[egc];

        // x[src]: lane needs d in [half*8, half*8+8) and +16
        const float* xp = x + src * 32 + half * 8;
        float4 xa = *(const float4*)xp;
        float4 xb = *(const float4*)(xp + 4);
        float4 xc = *(const float4*)(xp + 16);
        float4 xd = *(const float4*)(xp + 20);
        float xlo[8] = {xa.x, xa.y, xa.z, xa.w, xb.x, xb.y, xb.z, xb.w};
        float xhi[8] = {xc.x, xc.y, xc.z, xc.w, xd.x, xd.y, xd.z, xd.w};

        // ea fragment (A and B layouts coincide): lane l -> ea[l&31][(l>>5)*8+j]
        const float* epp = ea + (size_t)egc * 16 + half * 8;
        float4 e0 = *(const float4*)epp;
        float4 e1 = *(const float4*)(epp + 4);
        s16x8 eaf;
        eaf[0]=bfs(e0.x); eaf[1]=bfs(e0.y); eaf[2]=bfs(e0.z); eaf[3]=bfs(e0.w);
        eaf[4]=bfs(e1.x); eaf[5]=bfs(e1.y); eaf[6]=bfs(e1.z); eaf[7]=bfs(e1.w);

        // hT[k][e] = (ea @ w1)^T via operand swap
        f32x16 hc = {};
        hc = __builtin_amdgcn_mfma_f32_32x32x16_bf16(w1f, eaf, hc, 0, 0, 0);

        // own 8 elements (rows k = 16kh + (i&3)+8*(i>>2)+4*half), bias+relu
        float X8[8];
        if (kh == 0) {
            #pragma unroll
            for (int i = 0; i < 8; i++) X8[i] = fmaxf(hc[i]     + b1r[i], 0.f);
        } else {
            #pragma unroll
            for (int i = 0; i < 8; i++) X8[i] = fmaxf(hc[8 + i] + b1r[i], 0.f);
        }

        f32x16 acc = {};
        #pragma unroll
        for (int i = 0; i < 8; i++) {
            // exchange across the half boundary: lane^32 holds k_local + 4
            const float other = __shfl_xor(X8[i], 32);
            const float hA = half ? other : X8[i];   // h[16kh + kA]
            const float hB = half ? X8[i] : other;   // h[16kh + kA + 4]
            const int kA = (i & 3) + 8 * (i >> 2);
            {
                s16x8 alo, ahi;
                #pragma unroll
                for (int j = 0; j < 8; j++) alo[j] = bfs(hA * xlo[j]);
                #pragma unroll
                for (int j = 0; j < 8; j++) ahi[j] = bfs(hA * xhi[j]);
                s16x8 blo = *(const s16x8*)(sw2 + (2 * kA)     * 256 + lane * 4);
                s16x8 bhi = *(const s16x8*)(sw2 + (2 * kA + 1) * 256 + lane * 4);
                acc = __builtin_amdgcn_mfma_f32_32x32x16_bf16(alo, blo, acc, 0, 0, 0);
                acc = __builtin_amdgcn_mfma_f32_32x32x16_bf16(ahi, bhi, acc, 0, 0, 0);
            }
            {
                const int kB = kA + 4;
                s16x8 alo, ahi;
                #pragma unroll
                for (int j = 0; j < 8; j++) alo[j] = bfs(hB * xlo[j]);
                #pragma unroll
                for (int j = 0; j < 8; j++) ahi[j] = bfs(hB * xhi[j]);
                s16x8 blo = *(const s16x8*)(sw2 + (2 * kB)     * 256 + lane * 4);
                s16x8 bhi = *(const s16x8*)(sw2 + (2 * kB + 1) * 256 + lane * 4);
                acc = __builtin_amdgcn_mfma_f32_32x32x16_bf16(alo, blo, acc, 0, 0, 0);
                acc = __builtin_amdgcn_mfma_f32_32x32x16_bf16(ahi, bhi, acc, 0, 0, 0);
            }
        }
        // b2 rows (h == 1): step 32 of this half-image
        {
            s16x8 ab;
            if (kh == 0) {
                #pragma unroll
                for (int j = 0; j < 8; j++) ab[j] = bfs(xlo[j]);
            } else {
                #pragma unroll
                for (int j = 0; j < 8; j++) ab[j] = bfs(xhi[j]);
            }
            s16x8 bb = *(const s16x8*)(sw2 + 32 * 256 + lane * 4);
            acc = __builtin_amdgcn_mfma_f32_32x32x16_bf16(ab, bb, acc, 0, 0, 0);
        }

        // scatter partial: D row = edge e, col = hid = er0
        #pragma unroll
        for (int r = 0; r < 16; r++) {
            int e  = (r & 3) + 8 * (r >> 2) + 4 * half;
            int ge = B0 + e;
            if (ge < NE) {
                int d = ei[NE + ge];
                atomicAdd(&agg[d * 32 + er0], acc[r]);
            }
        }
        if (kh == 0 && lane < 32 && eg < NE)
            atomicAdd(&cnt[ei[NE + eg]], 1.0f);
    }
}

// ---------------------------------------------------------------------------
// node kernel (in-place on out, which holds agg)
// ---------------------------------------------------------------------------
__global__ __launch_bounds__(256) void node_kernel(
    const float* __restrict__ x, const float* __restrict__ root,
    const float* __restrict__ bias_conv, const float* __restrict__ w3,
    const float* __restrict__ b3, const float* __restrict__ cnt,
    float* __restrict__ out)
{
    __shared__ float xs[8][32];
    __shared__ float ms[8][32];
    const int li = threadIdx.x >> 5, hid = threadIdx.x & 31;
    const int n = blockIdx.x * 8 + li;

    xs[li][hid] = x[n * 32 + hid];
    __syncthreads();

    float xr = 0.f;
    #pragma unroll
    for (int t = 0; t < 32; t++) xr += xs[li][t] * root[t * 32 + hid];

    float c = cnt[n];
    float ic = 1.0f / fmaxf(c, 1.0f);
    float m = out[n * 32 + hid] * ic + xr + bias_conv[hid];
    ms[li][hid] = m;
    __syncthreads();

    float o = b3[hid];
    #pragma unroll
    for (int t = 0; t < 32; t++) {
        o += xs[li][t] * w3[t * 32 + hid];
        o += ms[li][t] * w3[(32 + t) * 32 + hid];
    }
    out[n * 32 + hid] = fmaxf(o, 0.f);
}

// ---------------------------------------------------------------------------
extern "C" void kernel_launch(void* const* d_in, const int* in_sizes, int n_in,
                              void* d_out, int out_size, void* d_ws, size_t ws_size,
                              hipStream_t stream) {
    const float* x    = (const float*)d_in[0];
    const int*   ei   = (const int*)  d_in[1];
    const float* ea   = (const float*)d_in[2];
    const float* w1   = (const float*)d_in[3];
    const float* b1   = (const float*)d_in[4];
    const float* w2   = (const float*)d_in[5];
    const float* b2   = (const float*)d_in[6];
    const float* root = (const float*)d_in[7];
    const float* bc   = (const float*)d_in[8];
    const float* w3   = (const float*)d_in[9];
    const float* b3   = (const float*)d_in[10];

    float*    out  = (float*)d_out;                          // doubles as agg
    float*    cnt  = (float*)d_ws;                           // 200000 B
    unsigned* w2pk = (unsigned*)((char*)d_ws + NN * sizeof(float)); // 67584 B

    prep_kernel<<<1678, 256, 0, stream>>>(w2, b2, w2pk, out, cnt);

    edge_kernel<<<2 * NBH, 512, 0, stream>>>(x, ei, ea, w1, b1, w2pk, out, cnt);

    node_kernel<<<NN / 8, 256, 0, stream>>>(x, root, bc, w3, b3, cnt, out);
}

// Round 5
// 144.874 us; speedup vs baseline: 1.6995x; 1.6995x over previous
//
#include <hip/hip_runtime.h>

#define NN 50000
#define NE 250000
#define NT 7813        // ceil(NE/32)
#define NBLK 512       // edge blocks: 2 per CU

typedef __attribute__((ext_vector_type(8)))  short    s16x8;
typedef __attribute__((ext_vector_type(16))) float    f32x16;
typedef __attribute__((ext_vector_type(4)))  unsigned u32x4;

__device__ __forceinline__ unsigned bf16r(float f) {
    unsigned u = __float_as_uint(f);
    return (u + 0x7fffu + ((u >> 16) & 1u)) >> 16;   // RNE
}
__device__ __forceinline__ short bfs(float f) {
    __bf16 b = (__bf16)f;
    return __builtin_bit_cast(short, b);
}

// ---------------------------------------------------------------------------
// prep (fused): pack w2ext = [w2 rows; b2 rows] (1056 x 32) into bf16
// B-fragment image [66 steps][64 lanes][4 dwords] (round-2 layout, proven),
// and zero agg (d_out) + cnt.
//   step s covers w2ext rows [16s, 16s+16); lane l, dword q ->
//   rows kk = 16s + (l>>5)*8 + 2q (+1), col = l&31
// ---------------------------------------------------------------------------
__global__ __launch_bounds__(256) void prep_kernel(
    const float* __restrict__ w2, const float* __restrict__ b2,
    unsigned* __restrict__ w2pk, float* __restrict__ agg,
    float* __restrict__ cnt)
{
    int g = blockIdx.x * 256 + threadIdx.x;
    if (g < 16896) {
        int s = g >> 8, l = (g >> 2) & 63, q = g & 3;
        int col = l & 31;
        int kk = s * 16 + (l >> 5) * 8 + 2 * q;
        float f0 = (kk < 1024) ? w2[(kk >> 5) * 1024 + (kk & 31) * 32 + col]
                               : b2[(kk - 1024) * 32 + col];
        int k1 = kk + 1;
        float f1 = (k1 < 1024) ? w2[(k1 >> 5) * 1024 + (k1 & 31) * 32 + col]
                               : b2[(k1 - 1024) * 32 + col];
        w2pk[g] = (bf16r(f1) << 16) | bf16r(f0);
    } else {
        int c = g - 16896;
        if (c < 400000)      ((float4*)agg)[c]          = float4{0.f,0.f,0.f,0.f};
        else if (c < 412500) ((float4*)cnt)[c - 400000] = float4{0.f,0.f,0.f,0.f};
    }
}

// ---------------------------------------------------------------------------
// edge kernel (full-K per block, single scatter per edge):
//  hT = mfma(w1f, eaf): D[row=k][col=e]          (proven round 4)
//  h-broadcast via __shfl_xor(.,32) + select     (proven round 4)
//  64 + 2(b2) MFMAs accumulate msg tile          (proven round 2)
//  one atomicAdd scatter per edge element        (proven rounds 1-2 cheap)
// ---------------------------------------------------------------------------
__global__ __launch_bounds__(512) void edge_kernel(
    const float* __restrict__ x, const int* __restrict__ ei,
    const float* __restrict__ ea, const float* __restrict__ w1,
    const float* __restrict__ b1, const unsigned* __restrict__ w2pk,
    float* __restrict__ agg, float* __restrict__ cnt)
{
    extern __shared__ unsigned sw2[];             // 66*256 dwords = 67584 B
    {
        const u32x4* srcp = (const u32x4*)w2pk;
        u32x4* dstp = (u32x4*)sw2;
        for (int c = threadIdx.x; c < 66 * 64; c += 512) dstp[c] = srcp[c];
    }
    __syncthreads();

    const int lane = threadIdx.x & 63;
    const int wave = threadIdx.x >> 6;
    const int er0  = lane & 31;     // edge row (A/D); hid col (B/D)
    const int half = lane >> 5;

    // w1 B-fragment (16x32): lane l -> w1[(l>>5)*8+j][l&31]
    s16x8 w1f;
    #pragma unroll
    for (int j = 0; j < 8; j++) w1f[j] = bfs(w1[(half * 8 + j) * 32 + er0]);
    // b1 for own hT rows k = (i&3)+8*(i>>2)+4*half
    float b1r[16];
    #pragma unroll
    for (int i = 0; i < 16; i++)
        b1r[i] = b1[(i & 3) + 8 * (i >> 2) + 4 * half];

    for (int tile = blockIdx.x * 8 + wave; tile < NT; tile += NBLK * 8) {
        const int B0  = tile * 32;
        const int eg  = B0 + er0;
        const int egc = eg < NE ? eg : NE - 1;
        const int src = ei[egc];

        // x[src]: lane needs d in [half*8, half*8+8) and +16
        const float* xp = x + src * 32 + half * 8;
        float4 xa = *(const float4*)xp;
        float4 xb = *(const float4*)(xp + 4);
        float4 xc = *(const float4*)(xp + 16);
        float4 xd = *(const float4*)(xp + 20);
        float xlo[8] = {xa.x, xa.y, xa.z, xa.w, xb.x, xb.y, xb.z, xb.w};
        float xhi[8] = {xc.x, xc.y, xc.z, xc.w, xd.x, xd.y, xd.z, xd.w};

        // ea fragment (A and B layouts coincide): lane l -> ea[l&31][(l>>5)*8+j]
        const float* epp = ea + (size_t)egc * 16 + half * 8;
        float4 e0 = *(const float4*)epp;
        float4 e1 = *(const float4*)(epp + 4);
        s16x8 eaf;
        eaf[0]=bfs(e0.x); eaf[1]=bfs(e0.y); eaf[2]=bfs(e0.z); eaf[3]=bfs(e0.w);
        eaf[4]=bfs(e1.x); eaf[5]=bfs(e1.y); eaf[6]=bfs(e1.z); eaf[7]=bfs(e1.w);

        // hT[k][e] = (ea @ w1)^T via operand swap; bias + relu
        f32x16 hc = {};
        hc = __builtin_amdgcn_mfma_f32_32x32x16_bf16(w1f, eaf, hc, 0, 0, 0);
        float X16[16];
        #pragma unroll
        for (int i = 0; i < 16; i++) X16[i] = fmaxf(hc[i] + b1r[i], 0.f);

        f32x16 acc = {};
        #pragma unroll
        for (int i = 0; i < 16; i++) {
            // lane^32 holds k +/- 4; select so hA = h[kA], hB = h[kA+4]
            const float other = __shfl_xor(X16[i], 32);
            const float hA = half ? other : X16[i];
            const float hB = half ? X16[i] : other;
            const int kA = (i & 3) + 8 * (i >> 2);
            {
                s16x8 alo, ahi;
                #pragma unroll
                for (int j = 0; j < 8; j++) alo[j] = bfs(hA * xlo[j]);
                #pragma unroll
                for (int j = 0; j < 8; j++) ahi[j] = bfs(hA * xhi[j]);
                s16x8 blo = *(const s16x8*)(sw2 + (2 * kA)     * 256 + lane * 4);
                s16x8 bhi = *(const s16x8*)(sw2 + (2 * kA + 1) * 256 + lane * 4);
                acc = __builtin_amdgcn_mfma_f32_32x32x16_bf16(alo, blo, acc, 0, 0, 0);
                acc = __builtin_amdgcn_mfma_f32_32x32x16_bf16(ahi, bhi, acc, 0, 0, 0);
            }
            {
                const int kB = kA + 4;
                s16x8 alo, ahi;
                #pragma unroll
                for (int j = 0; j < 8; j++) alo[j] = bfs(hB * xlo[j]);
                #pragma unroll
                for (int j = 0; j < 8; j++) ahi[j] = bfs(hB * xhi[j]);
                s16x8 blo = *(const s16x8*)(sw2 + (2 * kB)     * 256 + lane * 4);
                s16x8 bhi = *(const s16x8*)(sw2 + (2 * kB + 1) * 256 + lane * 4);
                acc = __builtin_amdgcn_mfma_f32_32x32x16_bf16(alo, blo, acc, 0, 0, 0);
                acc = __builtin_amdgcn_mfma_f32_32x32x16_bf16(ahi, bhi, acc, 0, 0, 0);
            }
        }
        // b2 rows (h == 1): steps 64, 65
        {
            s16x8 alo, ahi;
            #pragma unroll
            for (int j = 0; j < 8; j++) alo[j] = bfs(xlo[j]);
            #pragma unroll
            for (int j = 0; j < 8; j++) ahi[j] = bfs(xhi[j]);
            s16x8 b64 = *(const s16x8*)(sw2 + 64 * 256 + lane * 4);
            s16x8 b65 = *(const s16x8*)(sw2 + 65 * 256 + lane * 4);
            acc = __builtin_amdgcn_mfma_f32_32x32x16_bf16(alo, b64, acc, 0, 0, 0);
            acc = __builtin_amdgcn_mfma_f32_32x32x16_bf16(ahi, b65, acc, 0, 0, 0);
        }

        // scatter: D row = edge e, col = hid = er0 (single pass per edge)
        #pragma unroll
        for (int r = 0; r < 16; r++) {
            int e  = (r & 3) + 8 * (r >> 2) + 4 * half;
            int ge = B0 + e;
            if (ge < NE) {
                int d = ei[NE + ge];
                atomicAdd(&agg[d * 32 + er0], acc[r]);
            }
        }
        if (lane < 32 && eg < NE)
            atomicAdd(&cnt[ei[NE + eg]], 1.0f);
    }
}

// ---------------------------------------------------------------------------
// node kernel (in-place on out, which holds agg)
// ---------------------------------------------------------------------------
__global__ __launch_bounds__(256) void node_kernel(
    const float* __restrict__ x, const float* __restrict__ root,
    const float* __restrict__ bias_conv, const float* __restrict__ w3,
    const float* __restrict__ b3, const float* __restrict__ cnt,
    float* __restrict__ out)
{
    __shared__ float xs[8][32];
    __shared__ float ms[8][32];
    const int li = threadIdx.x >> 5, hid = threadIdx.x & 31;
    const int n = blockIdx.x * 8 + li;

    xs[li][hid] = x[n * 32 + hid];
    __syncthreads();

    float xr = 0.f;
    #pragma unroll
    for (int t = 0; t < 32; t++) xr += xs[li][t] * root[t * 32 + hid];

    float c = cnt[n];
    float ic = 1.0f / fmaxf(c, 1.0f);
    float m = out[n * 32 + hid] * ic + xr + bias_conv[hid];
    ms[li][hid] = m;
    __syncthreads();

    float o = b3[hid];
    #pragma unroll
    for (int t = 0; t < 32; t++) {
        o += xs[li][t] * w3[t * 32 + hid];
        o += ms[li][t] * w3[(32 + t) * 32 + hid];
    }
    out[n * 32 + hid] = fmaxf(o, 0.f);
}

// ---------------------------------------------------------------------------
extern "C" void kernel_launch(void* const* d_in, const int* in_sizes, int n_in,
                              void* d_out, int out_size, void* d_ws, size_t ws_size,
                              hipStream_t stream) {
    const float* x    = (const float*)d_in[0];
    const int*   ei   = (const int*)  d_in[1];
    const float* ea   = (const float*)d_in[2];
    const float* w1   = (const float*)d_in[3];
    const float* b1   = (const float*)d_in[4];
    const float* w2   = (const float*)d_in[5];
    const float* b2   = (const float*)d_in[6];
    const float* root = (const float*)d_in[7];
    const float* bc   = (const float*)d_in[8];
    const float* w3   = (const float*)d_in[9];
    const float* b3   = (const float*)d_in[10];

    float*    out  = (float*)d_out;                          // doubles as agg
    float*    cnt  = (float*)d_ws;                           // 200000 B
    unsigned* w2pk = (unsigned*)((char*)d_ws + NN * sizeof(float)); // 67584 B

    prep_kernel<<<1678, 256, 0, stream>>>(w2, b2, w2pk, out, cnt);

    const int lds_bytes = 66 * 1024;                         // 67584
    hipFuncSetAttribute((const void*)edge_kernel,
                        hipFuncAttributeMaxDynamicSharedMemorySize, lds_bytes);
    edge_kernel<<<NBLK, 512, lds_bytes, stream>>>(x, ei, ea, w1, b1, w2pk, out, cnt);

    node_kernel<<<NN / 8, 256, 0, stream>>>(x, root, bc, w3, b3, cnt, out);
}